// Round 5
// baseline (26806.647 us; speedup 1.0000x reference)
//
#include <hip/hip_runtime.h>
#include <hip/hip_bf16.h>

#define NH1   1024
#define NH2   512
#define T_SEQ 256
#define T_TOT 288

typedef short short8 __attribute__((ext_vector_type(8)));
typedef float f32x4 __attribute__((ext_vector_type(4)));

union FragU { short8 s; unsigned short u[8]; };

__device__ __forceinline__ unsigned short f2bf(float x) {
    __hip_bfloat16 b = __float2bfloat16(x);
    return __builtin_bit_cast(unsigned short, b);
}
__device__ __forceinline__ float bf2f(unsigned short u) {
    unsigned int v = ((unsigned int)u) << 16;
    return __builtin_bit_cast(float, v);
}
__device__ __forceinline__ float sigf(float x) {
    return 1.0f / (1.0f + __expf(-x));
}
__device__ __forceinline__ float tanh_fast(float x) {
    float e = __expf(2.0f * fabsf(x));
    float t = 1.0f - 2.0f / (1.0f + e);
    return copysignf(t, x);
}

// Custom grid barrier: block bid writes flags[bid*32]=phase (release);
// threads 0..255 each poll one flag. Poison init (negative int) < phase 1,
// so no flag initialization needed. ~1 store + 1 L3 round trip vs the
// serialized atomic counter + s_sleep backoff inside ockl grid sync.
__device__ __forceinline__ void gbar(int* flags, int phase) {
    __threadfence();                 // release: drain + make prior stores visible
    __syncthreads();                 // whole block arrived
    if (threadIdx.x == 0)
        __hip_atomic_store(flags + (int)blockIdx.x * 32, phase,
                           __ATOMIC_RELEASE, __HIP_MEMORY_SCOPE_AGENT);
    if (threadIdx.x < 256) {
        while (__hip_atomic_load(flags + (int)threadIdx.x * 32,
                                 __ATOMIC_RELAXED, __HIP_MEMORY_SCOPE_AGENT) < phase) {
        }
    }
    __syncthreads();
    __threadfence();                 // acquire: invalidate stale cached lines
}

// input [T][B=64][512] fp32 -> xThi/xTlo [t][k8=64][b=64][8] bf16 (hi + residual lo)
__global__ void prep_x(const float* __restrict__ in,
                       unsigned short* __restrict__ xThi,
                       unsigned short* __restrict__ xTlo) {
    int t = blockIdx.x;
    const float* src = in + (size_t)t * (64 * 512);
    for (int idx = threadIdx.x; idx < 4096; idx += 256) {
        int k8 = idx >> 6, b = idx & 63;
        FragU hi, lo;
#pragma unroll
        for (int i = 0; i < 8; ++i) {
            float v = src[b * 512 + k8 * 8 + i];
            unsigned short h = f2bf(v);
            hi.u[i] = h;
            lo.u[i] = f2bf(v - bf2f(h));
        }
        size_t o = (size_t)t * 32768 + (size_t)k8 * 512 + b * 8;
        *(short8*)(xThi + o) = hi.s;
        *(short8*)(xTlo + o) = lo.s;
    }
}

// Persistent cooperative kernel: 256 blocks x 512 threads (8 waves).
// Same MFMA structure as round 4; only the grid barrier changed.
__global__ void __launch_bounds__(512, 2)
lstm_mfma(const float* __restrict__ Wih1, const float* __restrict__ Whh1,
          const float* __restrict__ bih1, const float* __restrict__ bhh1,
          const float* __restrict__ Wih2, const float* __restrict__ Whh2,
          const float* __restrict__ bih2, const float* __restrict__ bhh2,
          unsigned short* ws_us, float* __restrict__ out)
{
    __shared__ f32x4 red[2048];   // 8 partials x 4 N-tiles x 64 lanes = 32KB

    const int tid  = threadIdx.x;
    const int lane = tid & 63;
    const int w    = tid >> 6;      // wave 0..7
    const int bid  = blockIdx.x;
    const int lhi  = lane >> 4;     // 0..3
    const int llo  = lane & 15;

    // ---- workspace carve (ushort units) ----
    unsigned short* xThi  = ws_us;
    unsigned short* xTlo  = xThi + 8388608;
    unsigned short* h1Ahi = xTlo + 8388608;
    unsigned short* h1Alo = h1Ahi + 65536;
    unsigned short* h1Bhi = h1Alo + 65536;
    unsigned short* h1Blo = h1Bhi + 65536;
    unsigned short* h2Ahi = h1Blo + 65536;
    unsigned short* h2Alo = h2Ahi + 32768;
    unsigned short* h2Bhi = h2Alo + 32768;
    unsigned short* h2Blo = h2Bhi + 32768;
    int* flags = (int*)(h2Blo + 32768);   // 256 x 128B-padded barrier flags

    // ---- zero all state buffers (ws is poisoned each launch) ----
    {
        unsigned int* z = (unsigned int*)h1Ahi;   // 196608 u32 total
        int gid = bid * 512 + tid;                // 131072 threads
        z[gid] = 0u;
        if (gid < 65536) z[gid + 131072] = 0u;
    }

    // ---- one-time: weights -> per-lane A-fragments (hi/lo bf16) ----
    const int wK = w * 192;
    short8 A1h[6], A1l[6], A2h[6], A2l[6];
    {
        int r  = llo;
        int G1 = (r & 3) * NH1 + bid * 4 + (r >> 2);
#pragma unroll
        for (int s = 0; s < 6; ++s) {
            int k = wK + s * 32 + lhi * 8;
            const float* src = (k < 512) ? (Wih1 + (size_t)G1 * 512 + k)
                                         : (Whh1 + (size_t)G1 * 1024 + (k - 512));
            FragU h, l;
#pragma unroll
            for (int i = 0; i < 8; ++i) {
                float v = src[i];
                unsigned short hb = f2bf(v);
                h.u[i] = hb;
                l.u[i] = f2bf(v - bf2f(hb));
            }
            A1h[s] = h.s; A1l[s] = l.s;
        }
        bool valid2 = (r >> 2) < 2;   // only 8 real L2 rows; 8..15 are zero pad
        int G2 = (r & 3) * NH2 + bid * 2 + ((r >> 2) < 2 ? (r >> 2) : 0);
#pragma unroll
        for (int s = 0; s < 6; ++s) {
            FragU h, l;
#pragma unroll
            for (int i = 0; i < 8; ++i) { h.u[i] = 0; l.u[i] = 0; }
            if (valid2) {
                int k = wK + s * 32 + lhi * 8;
                const float* src = (k < 1024) ? (Wih2 + (size_t)G2 * 1024 + k)
                                              : (Whh2 + (size_t)G2 * 512 + (k - 1024));
#pragma unroll
                for (int i = 0; i < 8; ++i) {
                    float v = src[i];
                    unsigned short hb = f2bf(v);
                    h.u[i] = hb;
                    l.u[i] = f2bf(v - bf2f(hb));
                }
            }
            A2h[s] = h.s; A2l[s] = l.s;
        }
    }

    // ---- biases: lane's unit is lhi (L1) / lhi<2 (L2) ----
    float b1[4], b2[4];
#pragma unroll
    for (int g = 0; g < 4; ++g) {
        int r1 = g * NH1 + bid * 4 + lhi;
        b1[g] = bih1[r1] + bhh1[r1];
        int r2 = g * NH2 + bid * 2 + ((lhi < 2) ? lhi : 0);
        b2[g] = bih2[r2] + bhh2[r2];
    }

    const int laneoff = lhi * 512 + llo * 8;   // ushort offset within a k8-slab

    float c1 = 0.0f, c2 = 0.0f;
    unsigned short *h1c_hi = h1Ahi, *h1c_lo = h1Alo, *h1n_hi = h1Bhi, *h1n_lo = h1Blo;
    unsigned short *h2c_hi = h2Ahi, *h2c_lo = h2Alo, *h2n_hi = h2Bhi, *h2n_lo = h2Blo;

    int ph = 1;
    gbar(flags, ph);   // states zeroed everywhere

    for (int t = 0; t < T_TOT; ++t) {
        const bool seq = (t < T_SEQ);

        // ================= Layer 1: K-slice partial via MFMA =================
        f32x4 acc[4] = {{0,0,0,0},{0,0,0,0},{0,0,0,0},{0,0,0,0}};
#pragma unroll
        for (int s = 0; s < 6; ++s) {
            int k0 = wK + s * 32;
            const unsigned short *bh, *bl;
            if (seq) {
                if (k0 < 512) { size_t o = (size_t)t * 32768 + (size_t)(k0 >> 3) * 512; bh = xThi + o; bl = xTlo + o; }
                else          { int o = ((k0 - 512) >> 3) * 512; bh = h1c_hi + o; bl = h1c_lo + o; }
            } else {
                if (k0 < 512) { int o = (k0 >> 3) * 512; bh = h2c_hi + o; bl = h2c_lo + o; }
                else          { int o = ((k0 - 512) >> 3) * 512; bh = h1c_hi + o; bl = h1c_lo + o; }
            }
            const short8* ph4 = (const short8*)(bh + laneoff);
            const short8* pl4 = (const short8*)(bl + laneoff);
#pragma unroll
            for (int nt = 0; nt < 4; ++nt) {
                short8 Bh = ph4[nt * 16];
                short8 Bl = pl4[nt * 16];
                acc[nt] = __builtin_amdgcn_mfma_f32_16x16x32_bf16(A1h[s], Bh, acc[nt], 0, 0, 0);
                acc[nt] = __builtin_amdgcn_mfma_f32_16x16x32_bf16(A1l[s], Bh, acc[nt], 0, 0, 0);
                acc[nt] = __builtin_amdgcn_mfma_f32_16x16x32_bf16(A1h[s], Bl, acc[nt], 0, 0, 0);
            }
        }
        // ---- reduce 8 K-partials in LDS; wave nt finalizes batch tile nt ----
#pragma unroll
        for (int nt = 0; nt < 4; ++nt) red[(w * 4 + nt) * 64 + lane] = acc[nt];
        __syncthreads();
        if (w < 4) {
            f32x4 g = red[w * 64 + lane];
#pragma unroll
            for (int p = 1; p < 8; ++p) {
                f32x4 q = red[(p * 4 + w) * 64 + lane];
                g.x += q.x; g.y += q.y; g.z += q.z; g.w += q.w;
            }
            float iv = sigf(g.x + b1[0]);
            float fv = sigf(g.y + b1[1]);
            float gv = tanh_fast(g.z + b1[2]);
            float ov = sigf(g.w + b1[3]);
            c1 = fv * c1 + iv * gv;
            float h = ov * tanh_fast(c1);
            int b = w * 16 + llo;
            int j = bid * 4 + lhi;
            unsigned short hh = f2bf(h);
            unsigned short hl = f2bf(h - bf2f(hh));
            int o = (j >> 3) * 512 + b * 8 + (j & 7);
            h1n_hi[o] = hh; h1n_lo[o] = hl;
        }
        gbar(flags, ++ph);   // h1n visible to all blocks (also orders red reuse)

        // ================= Layer 2 =================
        f32x4 ac2[4] = {{0,0,0,0},{0,0,0,0},{0,0,0,0},{0,0,0,0}};
#pragma unroll
        for (int s = 0; s < 6; ++s) {
            int k0 = wK + s * 32;
            const unsigned short *bh, *bl;
            if (k0 < 1024) { int o = (k0 >> 3) * 512; bh = h1n_hi + o; bl = h1n_lo + o; }
            else           { int o = ((k0 - 1024) >> 3) * 512; bh = h2c_hi + o; bl = h2c_lo + o; }
            const short8* ph4 = (const short8*)(bh + laneoff);
            const short8* pl4 = (const short8*)(bl + laneoff);
#pragma unroll
            for (int nt = 0; nt < 4; ++nt) {
                short8 Bh = ph4[nt * 16];
                short8 Bl = pl4[nt * 16];
                ac2[nt] = __builtin_amdgcn_mfma_f32_16x16x32_bf16(A2h[s], Bh, ac2[nt], 0, 0, 0);
                ac2[nt] = __builtin_amdgcn_mfma_f32_16x16x32_bf16(A2l[s], Bh, ac2[nt], 0, 0, 0);
                ac2[nt] = __builtin_amdgcn_mfma_f32_16x16x32_bf16(A2h[s], Bl, ac2[nt], 0, 0, 0);
            }
        }
#pragma unroll
        for (int nt = 0; nt < 4; ++nt) red[(w * 4 + nt) * 64 + lane] = ac2[nt];
        __syncthreads();
        if (w < 4) {
            f32x4 g = red[w * 64 + lane];
#pragma unroll
            for (int p = 1; p < 8; ++p) {
                f32x4 q = red[(p * 4 + w) * 64 + lane];
                g.x += q.x; g.y += q.y; g.z += q.z; g.w += q.w;
            }
            if (lhi < 2) {
                float iv = sigf(g.x + b2[0]);
                float fv = sigf(g.y + b2[1]);
                float gv = tanh_fast(g.z + b2[2]);
                float ov = sigf(g.w + b2[3]);
                c2 = fv * c2 + iv * gv;
                float h = ov * tanh_fast(c2);
                int b  = w * 16 + llo;
                int j2 = bid * 2 + lhi;
                unsigned short hh = f2bf(h);
                unsigned short hl = f2bf(h - bf2f(hh));
                int o = (j2 >> 3) * 512 + b * 8 + (j2 & 7);
                h2n_hi[o] = hh; h2n_lo[o] = hl;
                out[(size_t)b * (T_TOT * NH2) + (size_t)t * NH2 + j2] = h;
            }
        }
        __syncthreads();   // red reads done before next step's L1 writes

        // future phase: next L1 consumes h2n -> full grid ordering needed
        if (t >= T_SEQ - 1) gbar(flags, ++ph);

        unsigned short* tp;
        tp = h1c_hi; h1c_hi = h1n_hi; h1n_hi = tp;
        tp = h1c_lo; h1c_lo = h1n_lo; h1n_lo = tp;
        tp = h2c_hi; h2c_hi = h2n_hi; h2n_hi = tp;
        tp = h2c_lo; h2c_lo = h2n_lo; h2n_lo = tp;
    }
}

extern "C" void kernel_launch(void* const* d_in, const int* in_sizes, int n_in,
                              void* d_out, int out_size, void* d_ws, size_t ws_size,
                              hipStream_t stream) {
    const float* input = (const float*)d_in[0];
    const float* W_ih1 = (const float*)d_in[1];
    const float* W_hh1 = (const float*)d_in[2];
    const float* b_ih1 = (const float*)d_in[3];
    const float* b_hh1 = (const float*)d_in[4];
    const float* W_ih2 = (const float*)d_in[5];
    const float* W_hh2 = (const float*)d_in[6];
    const float* b_ih2 = (const float*)d_in[7];
    const float* b_hh2 = (const float*)d_in[8];
    float* out = (float*)d_out;

    unsigned short* ws_us = (unsigned short*)d_ws;
    unsigned short* xThi  = ws_us;

    hipLaunchKernelGGL(prep_x, dim3(T_SEQ), dim3(256), 0, stream, input, xThi,
                       ws_us + 8388608);

    void* args[] = {
        (void*)&W_ih1, (void*)&W_hh1, (void*)&b_ih1, (void*)&b_hh1,
        (void*)&W_ih2, (void*)&W_hh2, (void*)&b_ih2, (void*)&b_hh2,
        (void*)&ws_us, (void*)&out
    };
    hipLaunchCooperativeKernel((void*)lstm_mfma, dim3(256), dim3(512), args, 0, stream);
}

// Round 8
// 26697.150 us; speedup vs baseline: 1.0041x; 1.0041x over previous
//
#include <hip/hip_runtime.h>
#include <hip/hip_bf16.h>

#define NH1   1024
#define NH2   512
#define T_SEQ 256
#define T_TOT 288

typedef short short8 __attribute__((ext_vector_type(8)));
typedef float f32x4 __attribute__((ext_vector_type(4)));

union FragU { short8 s; unsigned short u[8]; };

__device__ __forceinline__ unsigned short f2bf(float x) {
    __hip_bfloat16 b = __float2bfloat16(x);
    return __builtin_bit_cast(unsigned short, b);
}
__device__ __forceinline__ float bf2f(unsigned short u) {
    unsigned int v = ((unsigned int)u) << 16;
    return __builtin_bit_cast(float, v);
}
__device__ __forceinline__ float sigf(float x) {
    return 1.0f / (1.0f + __expf(-x));
}
__device__ __forceinline__ float tanh_fast(float x) {
    float e = __expf(2.0f * fabsf(x));
    float t = 1.0f - 2.0f / (1.0f + e);
    return copysignf(t, x);
}

// Hub-and-spoke grid barrier. No atomic RMW anywhere, ~511 spinners total:
//  - every block's thread0 release-stores flags[bid*32] = phase   (parallel)
//  - block0 threads 0..255 each poll ONE flag, then thread0 stores epoch
//  - other blocks: only thread0 spins on epoch (single read-shared line)
// flags/epoch are zeroed by prep_x (stream-ordered before this kernel).
__device__ __forceinline__ void gbar(int* flags, int* epoch, int p) {
    __threadfence();                 // release: drain prior global stores
    __syncthreads();                 // whole block arrived
    if (blockIdx.x == 0) {
        if (threadIdx.x < 256) {
            if (threadIdx.x == 0)
                __hip_atomic_store(flags, p, __ATOMIC_RELEASE, __HIP_MEMORY_SCOPE_AGENT);
            while (__hip_atomic_load(flags + threadIdx.x * 32,
                                     __ATOMIC_RELAXED, __HIP_MEMORY_SCOPE_AGENT) < p)
                __builtin_amdgcn_s_sleep(1);
        }
        __syncthreads();             // all 256 flags observed
        if (threadIdx.x == 0)
            __hip_atomic_store(epoch, p, __ATOMIC_RELEASE, __HIP_MEMORY_SCOPE_AGENT);
    } else {
        if (threadIdx.x == 0) {
            __hip_atomic_store(flags + (int)blockIdx.x * 32, p,
                               __ATOMIC_RELEASE, __HIP_MEMORY_SCOPE_AGENT);
            while (__hip_atomic_load(epoch, __ATOMIC_RELAXED,
                                     __HIP_MEMORY_SCOPE_AGENT) < p)
                __builtin_amdgcn_s_sleep(1);
        }
        __syncthreads();
    }
    __threadfence();                 // acquire: discard stale cached lines
}

// input [T][B=64][512] fp32 -> xThi/xTlo [t][k8=64][b=64][8] bf16 (hi + residual lo)
// Block 0 additionally zeroes the barrier flags/epoch region.
__global__ void prep_x(const float* __restrict__ in,
                       unsigned short* __restrict__ xThi,
                       unsigned short* __restrict__ xTlo,
                       int* __restrict__ barrier_mem) {
    int t = blockIdx.x;
    if (t == 0) {
        for (int i = threadIdx.x; i < 256 * 32 + 32; i += 256) barrier_mem[i] = 0;
    }
    const float* src = in + (size_t)t * (64 * 512);
    for (int idx = threadIdx.x; idx < 4096; idx += 256) {
        int k8 = idx >> 6, b = idx & 63;
        FragU hi, lo;
#pragma unroll
        for (int i = 0; i < 8; ++i) {
            float v = src[b * 512 + k8 * 8 + i];
            unsigned short h = f2bf(v);
            hi.u[i] = h;
            lo.u[i] = f2bf(v - bf2f(h));
        }
        size_t o = (size_t)t * 32768 + (size_t)k8 * 512 + b * 8;
        *(short8*)(xThi + o) = hi.s;
        *(short8*)(xTlo + o) = lo.s;
    }
}

// Persistent cooperative kernel: 256 blocks x 512 threads (8 waves).
// Same MFMA structure as round 4; only the grid barrier changed.
__global__ void __launch_bounds__(512, 2)
lstm_mfma(const float* __restrict__ Wih1, const float* __restrict__ Whh1,
          const float* __restrict__ bih1, const float* __restrict__ bhh1,
          const float* __restrict__ Wih2, const float* __restrict__ Whh2,
          const float* __restrict__ bih2, const float* __restrict__ bhh2,
          unsigned short* ws_us, float* __restrict__ out)
{
    __shared__ f32x4 red[2048];   // 8 partials x 4 N-tiles x 64 lanes = 32KB

    const int tid  = threadIdx.x;
    const int lane = tid & 63;
    const int w    = tid >> 6;      // wave 0..7
    const int bid  = blockIdx.x;
    const int lhi  = lane >> 4;     // 0..3
    const int llo  = lane & 15;

    // ---- workspace carve (ushort units) ----
    unsigned short* xThi  = ws_us;
    unsigned short* xTlo  = xThi + 8388608;
    unsigned short* h1Ahi = xTlo + 8388608;
    unsigned short* h1Alo = h1Ahi + 65536;
    unsigned short* h1Bhi = h1Alo + 65536;
    unsigned short* h1Blo = h1Bhi + 65536;
    unsigned short* h2Ahi = h1Blo + 65536;
    unsigned short* h2Alo = h2Ahi + 32768;
    unsigned short* h2Bhi = h2Alo + 32768;
    unsigned short* h2Blo = h2Bhi + 32768;
    int* flags = (int*)(h2Blo + 32768);   // 256 x 128B-padded arrive flags
    int* epoch = flags + 256 * 32;        // single release word

    // ---- zero all state buffers (ws is poisoned each launch) ----
    {
        unsigned int* z = (unsigned int*)h1Ahi;   // 196608 u32 total
        int gid = bid * 512 + tid;                // 131072 threads
        z[gid] = 0u;
        if (gid < 65536) z[gid + 131072] = 0u;
    }

    // ---- one-time: weights -> per-lane A-fragments (hi/lo bf16) ----
    const int wK = w * 192;
    short8 A1h[6], A1l[6], A2h[6], A2l[6];
    {
        int r  = llo;
        int G1 = (r & 3) * NH1 + bid * 4 + (r >> 2);
#pragma unroll
        for (int s = 0; s < 6; ++s) {
            int k = wK + s * 32 + lhi * 8;
            const float* src = (k < 512) ? (Wih1 + (size_t)G1 * 512 + k)
                                         : (Whh1 + (size_t)G1 * 1024 + (k - 512));
            FragU h, l;
#pragma unroll
            for (int i = 0; i < 8; ++i) {
                float v = src[i];
                unsigned short hb = f2bf(v);
                h.u[i] = hb;
                l.u[i] = f2bf(v - bf2f(hb));
            }
            A1h[s] = h.s; A1l[s] = l.s;
        }
        bool valid2 = (r >> 2) < 2;   // only 8 real L2 rows; 8..15 are zero pad
        int G2 = (r & 3) * NH2 + bid * 2 + ((r >> 2) < 2 ? (r >> 2) : 0);
#pragma unroll
        for (int s = 0; s < 6; ++s) {
            FragU h, l;
#pragma unroll
            for (int i = 0; i < 8; ++i) { h.u[i] = 0; l.u[i] = 0; }
            if (valid2) {
                int k = wK + s * 32 + lhi * 8;
                const float* src = (k < 1024) ? (Wih2 + (size_t)G2 * 1024 + k)
                                              : (Whh2 + (size_t)G2 * 512 + (k - 1024));
#pragma unroll
                for (int i = 0; i < 8; ++i) {
                    float v = src[i];
                    unsigned short hb = f2bf(v);
                    h.u[i] = hb;
                    l.u[i] = f2bf(v - bf2f(hb));
                }
            }
            A2h[s] = h.s; A2l[s] = l.s;
        }
    }

    // ---- biases: lane's unit is lhi (L1) / lhi<2 (L2) ----
    float b1[4], b2[4];
#pragma unroll
    for (int g = 0; g < 4; ++g) {
        int r1 = g * NH1 + bid * 4 + lhi;
        b1[g] = bih1[r1] + bhh1[r1];
        int r2 = g * NH2 + bid * 2 + ((lhi < 2) ? lhi : 0);
        b2[g] = bih2[r2] + bhh2[r2];
    }

    const int laneoff = lhi * 512 + llo * 8;   // ushort offset within a k8-slab

    float c1 = 0.0f, c2 = 0.0f;
    unsigned short *h1c_hi = h1Ahi, *h1c_lo = h1Alo, *h1n_hi = h1Bhi, *h1n_lo = h1Blo;
    unsigned short *h2c_hi = h2Ahi, *h2c_lo = h2Alo, *h2n_hi = h2Bhi, *h2n_lo = h2Blo;

    int ph = 1;
    gbar(flags, epoch, ph);   // states zeroed everywhere

    for (int t = 0; t < T_TOT; ++t) {
        const bool seq = (t < T_SEQ);

        // ================= Layer 1: K-slice partial via MFMA =================
        f32x4 acc[4] = {{0,0,0,0},{0,0,0,0},{0,0,0,0},{0,0,0,0}};
#pragma unroll
        for (int s = 0; s < 6; ++s) {
            int k0 = wK + s * 32;
            const unsigned short *bh, *bl;
            if (seq) {
                if (k0 < 512) { size_t o = (size_t)t * 32768 + (size_t)(k0 >> 3) * 512; bh = xThi + o; bl = xTlo + o; }
                else          { int o = ((k0 - 512) >> 3) * 512; bh = h1c_hi + o; bl = h1c_lo + o; }
            } else {
                if (k0 < 512) { int o = (k0 >> 3) * 512; bh = h2c_hi + o; bl = h2c_lo + o; }
                else          { int o = ((k0 - 512) >> 3) * 512; bh = h1c_hi + o; bl = h1c_lo + o; }
            }
            const short8* ph4 = (const short8*)(bh + laneoff);
            const short8* pl4 = (const short8*)(bl + laneoff);
#pragma unroll
            for (int nt = 0; nt < 4; ++nt) {
                short8 Bh = ph4[nt * 16];
                short8 Bl = pl4[nt * 16];
                acc[nt] = __builtin_amdgcn_mfma_f32_16x16x32_bf16(A1h[s], Bh, acc[nt], 0, 0, 0);
                acc[nt] = __builtin_amdgcn_mfma_f32_16x16x32_bf16(A1l[s], Bh, acc[nt], 0, 0, 0);
                acc[nt] = __builtin_amdgcn_mfma_f32_16x16x32_bf16(A1h[s], Bl, acc[nt], 0, 0, 0);
            }
        }
        // ---- reduce 8 K-partials in LDS; wave nt finalizes batch tile nt ----
#pragma unroll
        for (int nt = 0; nt < 4; ++nt) red[(w * 4 + nt) * 64 + lane] = acc[nt];
        __syncthreads();
        if (w < 4) {
            f32x4 g = red[w * 64 + lane];
#pragma unroll
            for (int p = 1; p < 8; ++p) {
                f32x4 q = red[(p * 4 + w) * 64 + lane];
                g.x += q.x; g.y += q.y; g.z += q.z; g.w += q.w;
            }
            float iv = sigf(g.x + b1[0]);
            float fv = sigf(g.y + b1[1]);
            float gv = tanh_fast(g.z + b1[2]);
            float ov = sigf(g.w + b1[3]);
            c1 = fv * c1 + iv * gv;
            float h = ov * tanh_fast(c1);
            int b = w * 16 + llo;
            int j = bid * 4 + lhi;
            unsigned short hh = f2bf(h);
            unsigned short hl = f2bf(h - bf2f(hh));
            int o = (j >> 3) * 512 + b * 8 + (j & 7);
            h1n_hi[o] = hh; h1n_lo[o] = hl;
        }
        gbar(flags, epoch, ++ph);   // h1n visible to all blocks

        // ================= Layer 2 =================
        f32x4 ac2[4] = {{0,0,0,0},{0,0,0,0},{0,0,0,0},{0,0,0,0}};
#pragma unroll
        for (int s = 0; s < 6; ++s) {
            int k0 = wK + s * 32;
            const unsigned short *bh, *bl;
            if (k0 < 1024) { int o = (k0 >> 3) * 512; bh = h1n_hi + o; bl = h1n_lo + o; }
            else           { int o = ((k0 - 1024) >> 3) * 512; bh = h2c_hi + o; bl = h2c_lo + o; }
            const short8* ph4 = (const short8*)(bh + laneoff);
            const short8* pl4 = (const short8*)(bl + laneoff);
#pragma unroll
            for (int nt = 0; nt < 4; ++nt) {
                short8 Bh = ph4[nt * 16];
                short8 Bl = pl4[nt * 16];
                ac2[nt] = __builtin_amdgcn_mfma_f32_16x16x32_bf16(A2h[s], Bh, ac2[nt], 0, 0, 0);
                ac2[nt] = __builtin_amdgcn_mfma_f32_16x16x32_bf16(A2l[s], Bh, ac2[nt], 0, 0, 0);
                ac2[nt] = __builtin_amdgcn_mfma_f32_16x16x32_bf16(A2h[s], Bl, ac2[nt], 0, 0, 0);
            }
        }
#pragma unroll
        for (int nt = 0; nt < 4; ++nt) red[(w * 4 + nt) * 64 + lane] = ac2[nt];
        __syncthreads();
        if (w < 4) {
            f32x4 g = red[w * 64 + lane];
#pragma unroll
            for (int p = 1; p < 8; ++p) {
                f32x4 q = red[(p * 4 + w) * 64 + lane];
                g.x += q.x; g.y += q.y; g.z += q.z; g.w += q.w;
            }
            if (lhi < 2) {
                float iv = sigf(g.x + b2[0]);
                float fv = sigf(g.y + b2[1]);
                float gv = tanh_fast(g.z + b2[2]);
                float ov = sigf(g.w + b2[3]);
                c2 = fv * c2 + iv * gv;
                float h = ov * tanh_fast(c2);
                int b  = w * 16 + llo;
                int j2 = bid * 2 + lhi;
                unsigned short hh = f2bf(h);
                unsigned short hl = f2bf(h - bf2f(hh));
                int o = (j2 >> 3) * 512 + b * 8 + (j2 & 7);
                h2n_hi[o] = hh; h2n_lo[o] = hl;
                out[(size_t)b * (T_TOT * NH2) + (size_t)t * NH2 + j2] = h;
            }
        }
        __syncthreads();   // red reads done before next step's L1 writes

        // future phase: next L1 consumes h2n -> full grid ordering needed
        if (t >= T_SEQ - 1) gbar(flags, epoch, ++ph);

        unsigned short* tp;
        tp = h1c_hi; h1c_hi = h1n_hi; h1n_hi = tp;
        tp = h1c_lo; h1c_lo = h1n_lo; h1n_lo = tp;
        tp = h2c_hi; h2c_hi = h2n_hi; h2n_hi = tp;
        tp = h2c_lo; h2c_lo = h2n_lo; h2n_lo = tp;
    }
}

extern "C" void kernel_launch(void* const* d_in, const int* in_sizes, int n_in,
                              void* d_out, int out_size, void* d_ws, size_t ws_size,
                              hipStream_t stream) {
    const float* input = (const float*)d_in[0];
    const float* W_ih1 = (const float*)d_in[1];
    const float* W_hh1 = (const float*)d_in[2];
    const float* b_ih1 = (const float*)d_in[3];
    const float* b_hh1 = (const float*)d_in[4];
    const float* W_ih2 = (const float*)d_in[5];
    const float* W_hh2 = (const float*)d_in[6];
    const float* b_ih2 = (const float*)d_in[7];
    const float* b_hh2 = (const float*)d_in[8];
    float* out = (float*)d_out;

    unsigned short* ws_us = (unsigned short*)d_ws;
    // barrier region lives after the state buffers:
    int* barrier_mem = (int*)(ws_us + 8388608 * 2 + 65536 * 4 + 32768 * 4);

    hipLaunchKernelGGL(prep_x, dim3(T_SEQ), dim3(256), 0, stream, input, ws_us,
                       ws_us + 8388608, barrier_mem);

    void* args[] = {
        (void*)&W_ih1, (void*)&W_hh1, (void*)&b_ih1, (void*)&b_hh1,
        (void*)&W_ih2, (void*)&W_hh2, (void*)&b_ih2, (void*)&b_hh2,
        (void*)&ws_us, (void*)&out
    };
    hipLaunchCooperativeKernel((void*)lstm_mfma, dim3(256), dim3(512), args, 0, stream);
}